// Round 6
// baseline (2030.726 us; speedup 1.0000x reference)
//
#include <hip/hip_runtime.h>
#include <math.h>

// Dims (fixed by the problem)
#define HH   50          // hidden
#define GG   150         // 3H
#define XGS  152         // xg row stride (padded)
#define TTT  2048        // T
#define NB   64          // batch B
#define MTOT (TTT*NB)    // 131072 rows per layer
#define D0   128         // layer-0 input dim

static __device__ __forceinline__ float sigm(float x) {
    return 1.f / (1.f + __expf(-x));
}
static __device__ __forceinline__ float tanh_f(float x) {
    return 1.f - 2.f / (__expf(2.f * x) + 1.f);   // saturates correctly at +/-inf
}

// ---------------- Projection: xg = Xin @ W + bi  (SGPR-row / VGPR-col) ----------------
// 3 waves/block; lane owns output column c = wave*64+lane, W column slice lives
// in VGPRs (loaded once per block). Row values are wave-uniform broadcast loads.
// Zero LDS. 2-row unroll for FMA ILP. Stores coalesced (lanes span cols).
// L0: Xin = x [64,2048,128], row m=t*64+b -> x[b][t][:] (16B-aligned, float4).
// else: Xin = Xbuf [MTOT,50] (8B-aligned rows, float2), K padded to 52 w/ zeros.
template<int K, int RB, bool L0>
__global__ __launch_bounds__(192) void proj_sv(
    const float* __restrict__ Xin,
    const float* __restrict__ W,              // [K,150] f32
    const float* __restrict__ bias,           // [2,150] f32 (bi = bias[0])
    float* __restrict__ xg)                   // [MTOT,XGS] f32
{
    constexpr int KP = (K + 3) & ~3;          // 128 or 52
    const int lane = threadIdx.x & 63;
    const int wv   = threadIdx.x >> 6;        // 0..2
    const int c    = wv * 64 + lane;          // 0..191; valid < 150
    const int cc   = (c < GG) ? c : (GG - 1);
    float wreg[KP];
    #pragma unroll
    for (int k = 0; k < KP; ++k)
        wreg[k] = (k < K) ? W[k * GG + cc] : 0.f;
    const float bv = bias[cc];
    const int m0 = blockIdx.x * RB;
    for (int r = 0; r < RB; r += 2) {
        const int m1 = m0 + r, m2 = m0 + r + 1;
        const float* x1;
        const float* x2;
        if (L0) {
            x1 = Xin + ((size_t)(m1 & 63) * TTT + (m1 >> 6)) * D0;
            x2 = Xin + ((size_t)(m2 & 63) * TTT + (m2 >> 6)) * D0;
        } else {
            x1 = Xin + (size_t)m1 * HH;
            x2 = Xin + (size_t)m2 * HH;
        }
        float a1 = bv, a2 = bv;
        if (L0) {
            #pragma unroll
            for (int kk = 0; kk < KP / 4; ++kk) {
                float4 v1 = *(const float4*)(x1 + kk * 4);
                float4 v2 = *(const float4*)(x2 + kk * 4);
                a1 += v1.x * wreg[4*kk] + v1.y * wreg[4*kk+1]
                    + v1.z * wreg[4*kk+2] + v1.w * wreg[4*kk+3];
                a2 += v2.x * wreg[4*kk] + v2.y * wreg[4*kk+1]
                    + v2.z * wreg[4*kk+2] + v2.w * wreg[4*kk+3];
            }
        } else {
            #pragma unroll
            for (int kk = 0; kk < KP / 2; ++kk) {
                float2 v1 = *(const float2*)(x1 + kk * 2);
                float2 v2 = *(const float2*)(x2 + kk * 2);
                a1 += v1.x * wreg[2*kk] + v1.y * wreg[2*kk+1];
                a2 += v2.x * wreg[2*kk] + v2.y * wreg[2*kk+1];
            }
        }
        if (c < GG) {
            xg[(size_t)m1 * XGS + c] = a1;
            xg[(size_t)m2 * XGS + c] = a2;
        }
    }
}

// ---------------- GRU recurrence, barrier-free wave-autonomous ----------------
// WPB waves/block, RPW rows/wave. Each wave owns RPW rows end-to-end; no
// __syncthreads in the step loop (per-wave DS ops are in-order). rec item =
// RPW rows x 4 cols: per k, 1 b128 of U + RPW/4 b128 of transposed h feed
// 4*RPW FMAs. br bias in registers; h_prev in gate-lane registers.
// Output permuted to time-major: n=j*64+b -> tau=j*dn+s.
template<int WPB, int RPW>
__global__ __launch_bounds__(WPB * 64) void gru_wave(
    const float* __restrict__ xg,             // [dn*Nbatch, XGS] f32 (includes bi)
    const float* __restrict__ U,              // [50,150] f32
    const float* __restrict__ bias,           // [2,150] f32 (br = bias+150)
    float* __restrict__ Xout,                 // [MTOT,50] f32 time-major
    int dn, int Nbatch)
{
    constexpr int R   = WPB * RPW;            // rows per block
    constexpr int LPR = 64 / RPW;             // gate lanes per row
    constexpr int NU  = (HH + LPR - 1) / LPR; // gate k values per lane
    __shared__ __align__(16) float Us[HH * XGS];      // 30.4 KB
    __shared__ __align__(16) float brs[XGS];
    __shared__ __align__(16) float hsT[HH][R];        // transposed h
    __shared__ __align__(16) float rc[R][XGS];        // rec result

    const int tid  = threadIdx.x;
    const int wav  = tid >> 6;
    const int lane = tid & 63;

    for (int i = tid; i < HH * XGS; i += WPB * 64) {
        int c = i % XGS;
        Us[i] = (c < GG) ? U[(i / XGS) * GG + c] : 0.f;
    }
    for (int i = tid; i < XGS; i += WPB * 64) brs[i] = (i < GG) ? bias[GG + i] : 0.f;
    for (int i = tid; i < HH * R; i += WPB * 64) ((float*)hsT)[i] = 0.f;
    __syncthreads();                          // the only block-wide barrier

    // rec role: lanes 0..37 own a 4-col group x this wave's RPW rows
    const int cg = lane;
    float4 brv = make_float4(0.f, 0.f, 0.f, 0.f);
    if (cg < 38) brv = *(const float4*)&brs[cg * 4];

    // gate role: lane = gr*LPR + gk handles (row gr, k = gk + LPR*u)
    const int gr = lane / LPR;
    const int gk = lane % LPR;
    const int nrow = blockIdx.x * R + wav * RPW + gr;
    const int jj = nrow >> 6, bb = nrow & 63;
    float hprev[NU];
    #pragma unroll
    for (int u = 0; u < NU; ++u) hprev[u] = 0.f;

    for (int s = 0; s < dn; ++s) {
        // ---- prefetch this step's gate inputs (lands during rec) ----
        float pz[NU], pr[NU], ph[NU];
        {
            const float* g = xg + ((size_t)s * Nbatch + nrow) * XGS;
            #pragma unroll
            for (int u = 0; u < NU; ++u) {
                int k = gk + LPR * u;
                if (k < HH) { pz[u] = g[k]; pr[u] = g[HH + k]; ph[u] = g[2 * HH + k]; }
            }
        }
        // ---- rec = h @ U + br (this wave's RPW rows x 152 cols) ----
        if (cg < 38) {
            float acc[RPW][4];
            #pragma unroll
            for (int j = 0; j < RPW; ++j) {
                acc[j][0] = brv.x; acc[j][1] = brv.y; acc[j][2] = brv.z; acc[j][3] = brv.w;
            }
            #pragma unroll
            for (int k = 0; k < HH; ++k) {
                float4 w = *(const float4*)&Us[k * XGS + cg * 4];
                float wc[4] = {w.x, w.y, w.z, w.w};
                float hj[RPW];
                {
                    float4 h0 = *(const float4*)&hsT[k][wav * RPW];
                    hj[0] = h0.x; hj[1] = h0.y; hj[2] = h0.z; hj[3] = h0.w;
                    if (RPW == 8) {
                        float4 h1 = *(const float4*)&hsT[k][wav * RPW + 4];
                        hj[4] = h1.x; hj[5] = h1.y; hj[6] = h1.z; hj[7] = h1.w;
                    }
                }
                #pragma unroll
                for (int j = 0; j < RPW; ++j)
                    #pragma unroll
                    for (int cidx = 0; cidx < 4; ++cidx) acc[j][cidx] += hj[j] * wc[cidx];
            }
            #pragma unroll
            for (int j = 0; j < RPW; ++j)
                *(float4*)&rc[wav * RPW + j][cg * 4] = *(const float4*)&acc[j][0];
        }
        // ---- gates + state update + permuted global store ----
        const float* rcrow = rc[wav * RPW + gr];
        #pragma unroll
        for (int u = 0; u < NU; ++u) {
            int k = gk + LPR * u;
            if (k < HH) {
                float rcz = rcrow[k];
                float rcr = rcrow[HH + k];
                float rch = rcrow[2 * HH + k];
                float z  = sigm(pz[u] + rcz);
                float rr = sigm(pr[u] + rcr);
                float hh = tanh_f(ph[u] + rr * rch);
                float hn = z * hprev[u] + (1.f - z) * hh;
                hprev[u] = hn;
                hsT[k][wav * RPW + gr] = hn;
                Xout[((size_t)(jj * dn + s) * NB + bb) * HH + k] = hn;
            }
        }
    }
}

// ---------------- dense2 stage 1: partial sums over K-chunks ----------------
// grid (25 col-tiles, 16 k-chunks of 100). Block: 64 batch x 64 cols tile,
// thread = 4x4 register tile fed by b128 LDS reads.
__global__ __launch_bounds__(256) void dense2_part(
    const float* __restrict__ X,              // [MTOT,50] f32 final layer (time-major)
    const float* __restrict__ W2,             // [1600,1600] f32
    float* __restrict__ hpart)                // [16,64,1600] f32 partials
{
    __shared__ __align__(16) float fsT[100][64];      // 25.6 KB  feats[f_local][b]
    __shared__ __align__(16) float wt[100][64];       // 25.6 KB  W2[f_local][c_local]
    const int c0 = blockIdx.x * 64;
    const int f0 = blockIdx.y * 100;
    const int tid = threadIdx.x;
    for (int i = tid; i < 100 * 64; i += 256) {
        int fl = i >> 6, b = i & 63;
        int f = f0 + fl;
        int j = f / HH, k = f % HH;           // feats[b, f] = X[2016+j, b, k]
        fsT[fl][b] = X[((size_t)(TTT - 32 + j) * NB + b) * HH + k];
        wt[fl][i & 63] = W2[(size_t)f * 1600 + c0 + (i & 63)];
    }
    __syncthreads();
    const int bg = tid >> 4;                  // 16 groups of 4 batch rows
    const int cq = tid & 15;                  // 16 groups of 4 cols
    float acc[4][4];
    #pragma unroll
    for (int j = 0; j < 4; ++j)
        #pragma unroll
        for (int cidx = 0; cidx < 4; ++cidx) acc[j][cidx] = 0.f;
    for (int fl = 0; fl < 100; ++fl) {
        float4 hb = *(const float4*)&fsT[fl][bg * 4];
        float4 wv = *(const float4*)&wt[fl][cq * 4];
        float hj[4] = {hb.x, hb.y, hb.z, hb.w};
        float wc[4] = {wv.x, wv.y, wv.z, wv.w};
        #pragma unroll
        for (int j = 0; j < 4; ++j)
            #pragma unroll
            for (int cidx = 0; cidx < 4; ++cidx) acc[j][cidx] += hj[j] * wc[cidx];
    }
    #pragma unroll
    for (int j = 0; j < 4; ++j) {
        size_t idx = ((size_t)blockIdx.y * 64 + bg * 4 + j) * 1600 + c0 + cq * 4;
        *(float4*)&hpart[idx] = *(const float4*)&acc[j][0];
    }
}

// ---------------- dense2 stage 2: reduce partials + bias + relu ----------------
__global__ __launch_bounds__(256) void dense2_reduce(
    const float* __restrict__ hpart,          // [16,64,1600]
    const float* __restrict__ b2,             // [1600]
    float* __restrict__ hout)                 // [64,1600]
{
    int i = blockIdx.x * 256 + threadIdx.x;   // 64*1600 total
    int b = i / 1600, c = i % 1600;
    float s = b2[c];
    #pragma unroll
    for (int p = 0; p < 16; ++p) s += hpart[((size_t)p * 64 + b) * 1600 + c];
    hout[(size_t)b * 1600 + c] = s > 0.f ? s : 0.f;
}

// ---------------- Classifier + softmax -> f32 out ----------------
__global__ __launch_bounds__(256) void cls_kernel(
    const float* __restrict__ hin,            // [64,1600] f32
    const float* __restrict__ Wc,             // [1600,41] f32
    const float* __restrict__ bc,             // [41] f32
    float* __restrict__ out)                  // [64,41] f32
{
    __shared__ float hrow[1600];
    __shared__ float part[41][8];
    __shared__ float lg[41];
    __shared__ float red[2];
    const int b = blockIdx.x;
    const int t = threadIdx.x;
    for (int i = t; i < 1600; i += 256) hrow[i] = hin[(size_t)b * 1600 + i];
    __syncthreads();
    const int cl = t % 41, ch = t / 41;       // 6 chunks x 41 classes (246 active)
    if (t < 246) {
        int fbeg = ch * 267;
        int fend = fbeg + 267; if (fend > 1600) fend = 1600;
        float a = 0.f;
        for (int f = fbeg; f < fend; ++f) a += hrow[f] * Wc[f * 41 + cl];
        part[cl][ch] = a;
    }
    __syncthreads();
    if (t < 41) {
        float s = bc[t];
        #pragma unroll
        for (int chh = 0; chh < 6; ++chh) s += part[t][chh];
        lg[t] = s;
    }
    __syncthreads();
    if (t == 0) {
        float mx = lg[0];
        for (int i = 1; i < 41; ++i) mx = fmaxf(mx, lg[i]);
        red[0] = mx;
    }
    __syncthreads();
    if (t < 41) lg[t] = expf(lg[t] - red[0]);
    __syncthreads();
    if (t == 0) {
        float sm = 0.f;
        for (int i = 0; i < 41; ++i) sm += lg[i];
        red[1] = 1.f / sm;
    }
    __syncthreads();
    if (t < 41) out[b * 41 + t] = lg[t] * red[1];
}

extern "C" void kernel_launch(void* const* d_in, const int* in_sizes, int n_in,
                              void* d_out, int out_size, void* d_ws, size_t ws_size,
                              hipStream_t stream)
{
    const float* x   = (const float*)d_in[0];    // [64,2048,128]
    const float* W0  = (const float*)d_in[1];    // [128,150]
    const float* U0  = (const float*)d_in[2];    // [50,150]
    const float* b0  = (const float*)d_in[3];    // [2,150]
    const float* Ws  = (const float*)d_in[4];    // [5,50,150]
    const float* Us  = (const float*)d_in[5];    // [5,50,150]
    const float* bs  = (const float*)d_in[6];    // [5,2,150]
    const float* W2  = (const float*)d_in[7];    // [1600,1600]
    const float* b2  = (const float*)d_in[8];    // [1600]
    const float* Wc  = (const float*)d_in[9];    // [1600,41]
    const float* bc  = (const float*)d_in[10];   // [41]

    float* xg    = (float*)d_ws;                      // MTOT*XGS f32  (79.7 MB)
    float* Xbuf  = xg + (size_t)MTOT * XGS;           // MTOT*50 f32   (26.2 MB)
    float* hbuf  = Xbuf + (size_t)MTOT * HH;          // 64*1600 f32
    float* hpart = xg;                                // 16*64*1600 f32 — xg dead by then

    static const int rates[6] = {32, 64, 128, 256, 512, 1024};

    // layer 0
    proj_sv<D0, 128, true><<<MTOT / 128, 192, 0, stream>>>(x, W0, b0, xg);
    gru_wave<2, 4><<<rates[0] * NB / 8, 128, 0, stream>>>(
        xg, U0, b0, Xbuf, TTT / rates[0], rates[0] * NB);

    for (int l = 1; l < 6; ++l) {
        const float* Wl = Ws + (size_t)(l - 1) * HH * GG;
        const float* Ul = Us + (size_t)(l - 1) * HH * GG;
        const float* bl = bs + (size_t)(l - 1) * 2 * GG;
        proj_sv<HH, 128, false><<<MTOT / 128, 192, 0, stream>>>(Xbuf, Wl, bl, xg);
        int rate = rates[l];
        int Nbatch = rate * NB;
        int dn = TTT / rate;
        if (l == 1) {
            gru_wave<4, 4><<<Nbatch / 16, 256, 0, stream>>>(xg, Ul, bl, Xbuf, dn, Nbatch);
        } else {
            gru_wave<4, 8><<<Nbatch / 32, 256, 0, stream>>>(xg, Ul, bl, Xbuf, dn, Nbatch);
        }
    }
    // head
    dense2_part<<<dim3(25, 16), 256, 0, stream>>>(Xbuf, W2, hpart);
    dense2_reduce<<<(64 * 1600) / 256, 256, 0, stream>>>(hpart, b2, hbuf);
    cls_kernel<<<NB, 256, 0, stream>>>(hbuf, Wc, bc, (float*)d_out);
}

// Round 7
// 1373.236 us; speedup vs baseline: 1.4788x; 1.4788x over previous
//
#include <hip/hip_runtime.h>
#include <math.h>

// Dims (fixed by the problem)
#define HH   50          // hidden
#define GG   150         // 3H
#define XGS  152         // xg row stride (padded)
#define TTT  2048        // T
#define NB   64          // batch B
#define MTOT (TTT*NB)    // 131072 rows per layer
#define D0   128         // layer-0 input dim

static __device__ __forceinline__ float sigm(float x) {
    return 1.f / (1.f + __expf(-x));
}
static __device__ __forceinline__ float tanh_f(float x) {
    return 1.f - 2.f / (__expf(2.f * x) + 1.f);   // saturates correctly at +/-inf
}

// ---------------- Projection: xg = Xin @ W + bi  (K-chunked, spill-free) ----------------
// 3 waves/block; lane owns output column c = wave*64+lane. K is processed in
// chunks of CS: wreg[CS] (<=32 VGPRs) + acc[16] stay in registers. Rows are
// wave-uniform broadcast loads (1 cache line per instr). Zero LDS.
// L0: Xin = x [64,2048,128], row m=t*64+b -> x[b][t][:] (float4 loads).
// else: Xin = Xbuf [MTOT,50] (float2 loads, K padded to 52, w=0 on the pad —
//       the 2-float overrun of the last row stays inside d_ws).
template<int K, int CS, bool L0>
__global__ __launch_bounds__(192) void proj_ck(
    const float* __restrict__ Xin,
    const float* __restrict__ W,              // [K,150] f32
    const float* __restrict__ bias,           // [2,150] f32 (bi = bias[0])
    float* __restrict__ xg)                   // [MTOT,XGS] f32
{
    constexpr int NCH = (K + CS - 1) / CS;
    const int lane = threadIdx.x & 63;
    const int wv   = threadIdx.x >> 6;        // 0..2
    const int c    = wv * 64 + lane;          // 0..191; valid < 150
    const int cc   = (c < GG) ? c : (GG - 1);
    const float bv = bias[cc];
    const int m0 = blockIdx.x * 16;
    size_t base;
    size_t rstride;
    if (L0) { base = ((size_t)(m0 & 63) * TTT + (m0 >> 6)) * D0; rstride = (size_t)TTT * D0; }
    else    { base = (size_t)m0 * HH;                             rstride = HH; }

    float acc[16];
    #pragma unroll
    for (int r = 0; r < 16; ++r) acc[r] = 0.f;

    for (int ch = 0; ch < NCH; ++ch) {
        float w[CS];
        #pragma unroll
        for (int j = 0; j < CS; ++j) {
            int k = ch * CS + j;
            w[j] = (k < K) ? W[k * GG + cc] : 0.f;
        }
        const float* xc = Xin + base + ch * CS;
        #pragma unroll
        for (int r = 0; r < 16; ++r) {
            const float* xr = xc + (size_t)r * rstride;
            float a = 0.f;
            if (L0) {
                #pragma unroll
                for (int jj = 0; jj < CS / 4; ++jj) {
                    float4 v = *(const float4*)(xr + 4 * jj);
                    a += v.x * w[4*jj] + v.y * w[4*jj+1] + v.z * w[4*jj+2] + v.w * w[4*jj+3];
                }
            } else {
                #pragma unroll
                for (int jj = 0; jj < CS / 2; ++jj) {
                    float2 v = *(const float2*)(xr + 2 * jj);
                    a += v.x * w[2*jj] + v.y * w[2*jj+1];
                }
            }
            acc[r] += a;
        }
    }
    if (c < GG) {
        #pragma unroll
        for (int r = 0; r < 16; ++r)
            xg[(size_t)(m0 + r) * XGS + c] = acc[r] + bv;
    }
}

// ---------------- GRU recurrence, barrier-free wave-autonomous ----------------
// WPB waves/block, RPW rows/wave. Each wave owns RPW rows end-to-end; no
// __syncthreads in the step loop (per-wave DS ops are in-order). rec item =
// RPW rows x 4 cols: per k, 1 b128 of U + RPW/4 b128 of transposed h feed
// 4*RPW FMAs. br bias in registers; h_prev in gate-lane registers.
// Output permuted to time-major: n=j*64+b -> tau=j*dn+s.
template<int WPB, int RPW>
__global__ __launch_bounds__(WPB * 64) void gru_wave(
    const float* __restrict__ xg,             // [dn*Nbatch, XGS] f32 (includes bi)
    const float* __restrict__ U,              // [50,150] f32
    const float* __restrict__ bias,           // [2,150] f32 (br = bias+150)
    float* __restrict__ Xout,                 // [MTOT,50] f32 time-major
    int dn, int Nbatch)
{
    constexpr int R   = WPB * RPW;            // rows per block
    constexpr int LPR = 64 / RPW;             // gate lanes per row
    constexpr int NU  = (HH + LPR - 1) / LPR; // gate k values per lane
    __shared__ __align__(16) float Us[HH * XGS];      // 30.4 KB
    __shared__ __align__(16) float brs[XGS];
    __shared__ __align__(16) float hsT[HH][R];        // transposed h
    __shared__ __align__(16) float rc[R][XGS];        // rec result

    const int tid  = threadIdx.x;
    const int wav  = tid >> 6;
    const int lane = tid & 63;

    for (int i = tid; i < HH * XGS; i += WPB * 64) {
        int c = i % XGS;
        Us[i] = (c < GG) ? U[(i / XGS) * GG + c] : 0.f;
    }
    for (int i = tid; i < XGS; i += WPB * 64) brs[i] = (i < GG) ? bias[GG + i] : 0.f;
    for (int i = tid; i < HH * R; i += WPB * 64) ((float*)hsT)[i] = 0.f;
    __syncthreads();                          // the only block-wide barrier

    // rec role: lanes 0..37 own a 4-col group x this wave's RPW rows
    const int cg = lane;
    float4 brv = make_float4(0.f, 0.f, 0.f, 0.f);
    if (cg < 38) brv = *(const float4*)&brs[cg * 4];

    // gate role: lane = gr*LPR + gk handles (row gr, k = gk + LPR*u)
    const int gr = lane / LPR;
    const int gk = lane % LPR;
    const int nrow = blockIdx.x * R + wav * RPW + gr;
    const int jj = nrow >> 6, bb = nrow & 63;
    float hprev[NU];
    #pragma unroll
    for (int u = 0; u < NU; ++u) hprev[u] = 0.f;

    for (int s = 0; s < dn; ++s) {
        // ---- prefetch this step's gate inputs (lands during rec) ----
        float pz[NU], pr[NU], ph[NU];
        {
            const float* g = xg + ((size_t)s * Nbatch + nrow) * XGS;
            #pragma unroll
            for (int u = 0; u < NU; ++u) {
                int k = gk + LPR * u;
                if (k < HH) { pz[u] = g[k]; pr[u] = g[HH + k]; ph[u] = g[2 * HH + k]; }
            }
        }
        // ---- rec = h @ U + br (this wave's RPW rows x 152 cols) ----
        if (cg < 38) {
            float acc[RPW][4];
            #pragma unroll
            for (int j = 0; j < RPW; ++j) {
                acc[j][0] = brv.x; acc[j][1] = brv.y; acc[j][2] = brv.z; acc[j][3] = brv.w;
            }
            #pragma unroll
            for (int k = 0; k < HH; ++k) {
                float4 w = *(const float4*)&Us[k * XGS + cg * 4];
                float wc[4] = {w.x, w.y, w.z, w.w};
                float hj[RPW];
                {
                    float4 h0 = *(const float4*)&hsT[k][wav * RPW];
                    hj[0] = h0.x; hj[1] = h0.y; hj[2] = h0.z; hj[3] = h0.w;
                    if (RPW == 8) {
                        float4 h1 = *(const float4*)&hsT[k][wav * RPW + 4];
                        hj[4] = h1.x; hj[5] = h1.y; hj[6] = h1.z; hj[7] = h1.w;
                    }
                }
                #pragma unroll
                for (int j = 0; j < RPW; ++j)
                    #pragma unroll
                    for (int cidx = 0; cidx < 4; ++cidx) acc[j][cidx] += hj[j] * wc[cidx];
            }
            #pragma unroll
            for (int j = 0; j < RPW; ++j)
                *(float4*)&rc[wav * RPW + j][cg * 4] = *(const float4*)&acc[j][0];
        }
        // ---- gates + state update + permuted global store ----
        const float* rcrow = rc[wav * RPW + gr];
        #pragma unroll
        for (int u = 0; u < NU; ++u) {
            int k = gk + LPR * u;
            if (k < HH) {
                float rcz = rcrow[k];
                float rcr = rcrow[HH + k];
                float rch = rcrow[2 * HH + k];
                float z  = sigm(pz[u] + rcz);
                float rr = sigm(pr[u] + rcr);
                float hh = tanh_f(ph[u] + rr * rch);
                float hn = z * hprev[u] + (1.f - z) * hh;
                hprev[u] = hn;
                hsT[k][wav * RPW + gr] = hn;
                Xout[((size_t)(jj * dn + s) * NB + bb) * HH + k] = hn;
            }
        }
    }
}

// ---------------- dense2 stage 1: partial sums over K-chunks ----------------
// grid (25 col-tiles, 16 k-chunks of 100). Block: 64 batch x 64 cols tile,
// thread = 4x4 register tile fed by b128 LDS reads.
__global__ __launch_bounds__(256) void dense2_part(
    const float* __restrict__ X,              // [MTOT,50] f32 final layer (time-major)
    const float* __restrict__ W2,             // [1600,1600] f32
    float* __restrict__ hpart)                // [16,64,1600] f32 partials
{
    __shared__ __align__(16) float fsT[100][64];      // 25.6 KB  feats[f_local][b]
    __shared__ __align__(16) float wt[100][64];       // 25.6 KB  W2[f_local][c_local]
    const int c0 = blockIdx.x * 64;
    const int f0 = blockIdx.y * 100;
    const int tid = threadIdx.x;
    for (int i = tid; i < 100 * 64; i += 256) {
        int fl = i >> 6, b = i & 63;
        int f = f0 + fl;
        int j = f / HH, k = f % HH;           // feats[b, f] = X[2016+j, b, k]
        fsT[fl][b] = X[((size_t)(TTT - 32 + j) * NB + b) * HH + k];
        wt[fl][i & 63] = W2[(size_t)f * 1600 + c0 + (i & 63)];
    }
    __syncthreads();
    const int bg = tid >> 4;                  // 16 groups of 4 batch rows
    const int cq = tid & 15;                  // 16 groups of 4 cols
    float acc[4][4];
    #pragma unroll
    for (int j = 0; j < 4; ++j)
        #pragma unroll
        for (int cidx = 0; cidx < 4; ++cidx) acc[j][cidx] = 0.f;
    for (int fl = 0; fl < 100; ++fl) {
        float4 hb = *(const float4*)&fsT[fl][bg * 4];
        float4 wv = *(const float4*)&wt[fl][cq * 4];
        float hj[4] = {hb.x, hb.y, hb.z, hb.w};
        float wc[4] = {wv.x, wv.y, wv.z, wv.w};
        #pragma unroll
        for (int j = 0; j < 4; ++j)
            #pragma unroll
            for (int cidx = 0; cidx < 4; ++cidx) acc[j][cidx] += hj[j] * wc[cidx];
    }
    #pragma unroll
    for (int j = 0; j < 4; ++j) {
        size_t idx = ((size_t)blockIdx.y * 64 + bg * 4 + j) * 1600 + c0 + cq * 4;
        *(float4*)&hpart[idx] = *(const float4*)&acc[j][0];
    }
}

// ---------------- dense2 stage 2: reduce partials + bias + relu ----------------
__global__ __launch_bounds__(256) void dense2_reduce(
    const float* __restrict__ hpart,          // [16,64,1600]
    const float* __restrict__ b2,             // [1600]
    float* __restrict__ hout)                 // [64,1600]
{
    int i = blockIdx.x * 256 + threadIdx.x;   // 64*1600 total
    int b = i / 1600, c = i % 1600;
    float s = b2[c];
    #pragma unroll
    for (int p = 0; p < 16; ++p) s += hpart[((size_t)p * 64 + b) * 1600 + c];
    hout[(size_t)b * 1600 + c] = s > 0.f ? s : 0.f;
}

// ---------------- Classifier + softmax -> f32 out ----------------
__global__ __launch_bounds__(256) void cls_kernel(
    const float* __restrict__ hin,            // [64,1600] f32
    const float* __restrict__ Wc,             // [1600,41] f32
    const float* __restrict__ bc,             // [41] f32
    float* __restrict__ out)                  // [64,41] f32
{
    __shared__ float hrow[1600];
    __shared__ float part[41][8];
    __shared__ float lg[41];
    __shared__ float red[2];
    const int b = blockIdx.x;
    const int t = threadIdx.x;
    for (int i = t; i < 1600; i += 256) hrow[i] = hin[(size_t)b * 1600 + i];
    __syncthreads();
    const int cl = t % 41, ch = t / 41;       // 6 chunks x 41 classes (246 active)
    if (t < 246) {
        int fbeg = ch * 267;
        int fend = fbeg + 267; if (fend > 1600) fend = 1600;
        float a = 0.f;
        for (int f = fbeg; f < fend; ++f) a += hrow[f] * Wc[f * 41 + cl];
        part[cl][ch] = a;
    }
    __syncthreads();
    if (t < 41) {
        float s = bc[t];
        #pragma unroll
        for (int chh = 0; chh < 6; ++chh) s += part[t][chh];
        lg[t] = s;
    }
    __syncthreads();
    if (t == 0) {
        float mx = lg[0];
        for (int i = 1; i < 41; ++i) mx = fmaxf(mx, lg[i]);
        red[0] = mx;
    }
    __syncthreads();
    if (t < 41) lg[t] = expf(lg[t] - red[0]);
    __syncthreads();
    if (t == 0) {
        float sm = 0.f;
        for (int i = 0; i < 41; ++i) sm += lg[i];
        red[1] = 1.f / sm;
    }
    __syncthreads();
    if (t < 41) out[b * 41 + t] = lg[t] * red[1];
}

extern "C" void kernel_launch(void* const* d_in, const int* in_sizes, int n_in,
                              void* d_out, int out_size, void* d_ws, size_t ws_size,
                              hipStream_t stream)
{
    const float* x   = (const float*)d_in[0];    // [64,2048,128]
    const float* W0  = (const float*)d_in[1];    // [128,150]
    const float* U0  = (const float*)d_in[2];    // [50,150]
    const float* b0  = (const float*)d_in[3];    // [2,150]
    const float* Ws  = (const float*)d_in[4];    // [5,50,150]
    const float* Us  = (const float*)d_in[5];    // [5,50,150]
    const float* bs  = (const float*)d_in[6];    // [5,2,150]
    const float* W2  = (const float*)d_in[7];    // [1600,1600]
    const float* b2  = (const float*)d_in[8];    // [1600]
    const float* Wc  = (const float*)d_in[9];    // [1600,41]
    const float* bc  = (const float*)d_in[10];   // [41]

    float* xg    = (float*)d_ws;                      // MTOT*XGS f32  (79.7 MB)
    float* Xbuf  = xg + (size_t)MTOT * XGS;           // MTOT*50 f32   (26.2 MB)
    float* hbuf  = Xbuf + (size_t)MTOT * HH;          // 64*1600 f32
    float* hpart = xg;                                // 16*64*1600 f32 — xg dead by then

    static const int rates[6] = {32, 64, 128, 256, 512, 1024};

    // layer 0
    proj_ck<D0, 32, true><<<MTOT / 16, 192, 0, stream>>>(x, W0, b0, xg);
    gru_wave<1, 4><<<rates[0] * NB / 4, 64, 0, stream>>>(
        xg, U0, b0, Xbuf, TTT / rates[0], rates[0] * NB);

    for (int l = 1; l < 6; ++l) {
        const float* Wl = Ws + (size_t)(l - 1) * HH * GG;
        const float* Ul = Us + (size_t)(l - 1) * HH * GG;
        const float* bl = bs + (size_t)(l - 1) * 2 * GG;
        proj_ck<HH, 26, false><<<MTOT / 16, 192, 0, stream>>>(Xbuf, Wl, bl, xg);
        int rate = rates[l];
        int Nbatch = rate * NB;
        int dn = TTT / rate;
        if (l == 1) {
            gru_wave<2, 4><<<Nbatch / 8, 128, 0, stream>>>(xg, Ul, bl, Xbuf, dn, Nbatch);
        } else {
            gru_wave<4, 8><<<Nbatch / 32, 256, 0, stream>>>(xg, Ul, bl, Xbuf, dn, Nbatch);
        }
    }
    // head
    dense2_part<<<dim3(25, 16), 256, 0, stream>>>(Xbuf, W2, hpart);
    dense2_reduce<<<(64 * 1600) / 256, 256, 0, stream>>>(hpart, b2, hbuf);
    cls_kernel<<<NB, 256, 0, stream>>>(hbuf, Wc, bc, (float*)d_out);
}

// Round 8
// 1252.836 us; speedup vs baseline: 1.6209x; 1.0961x over previous
//
#include <hip/hip_runtime.h>
#include <math.h>

// Dims (fixed by the problem)
#define HH   50          // hidden
#define GG   150         // 3H
#define XGS  152         // xg row stride (padded)
#define TTT  2048        // T
#define NB   64          // batch B
#define MTOT (TTT*NB)    // 131072 rows per layer
#define D0   128         // layer-0 input dim

static __device__ __forceinline__ float sigm(float x) {
    return 1.f / (1.f + __expf(-x));
}
static __device__ __forceinline__ float tanh_f(float x) {
    return 1.f - 2.f / (__expf(2.f * x) + 1.f);   // saturates correctly at +/-inf
}

// ---------------- Projection as tiled GEMM: xg = Xin @ W + bi ----------------
// Tile 64 rows x 64 cols, 256 threads, thread = 4x4 register tile. Per k-step
// of 4: 4 b128 of xs + 4 b128 of wt feed 64 FMAs (FMA-bound). xs row pitch
// chosen so 4 row-groups land 2-way on banks (free). grid (MTOT/64, 3).
// L0: rows m=t*64+b share t -> x[b][t][:], row-contiguous float4 staging.
// H:  Xin=[MTOT,50] slab-contiguous, k padded to 52 with zeros.
template<int KREAL, int KP, int XSP, bool L0>
__global__ __launch_bounds__(256) void proj_gemm(
    const float* __restrict__ Xin,
    const float* __restrict__ W,              // [KREAL,150] f32
    const float* __restrict__ bias,           // [2,150] f32 (bi = bias[0])
    float* __restrict__ xg)                   // [MTOT,XGS] f32
{
    __shared__ __align__(16) float xs[64][XSP];       // L0: 64x132=33.8KB, H: 64x52=13.3KB
    __shared__ __align__(16) float wt[KP][64];        // L0: 32KB, H: 13.3KB
    const int tid = threadIdx.x;
    const int m0 = blockIdx.x * 64;
    const int c0 = blockIdx.y * 64;
    if (L0) {
        const int t = m0 >> 6;                // all 64 rows share t, r = b
        for (int i = tid; i < 64 * (KP / 4); i += 256) {
            int r = i / (KP / 4), kq = i % (KP / 4);
            *(float4*)&xs[r][kq * 4] =
                *(const float4*)(Xin + ((size_t)r * TTT + t) * D0 + kq * 4);
        }
    } else {
        for (int i = tid; i < 64 * KP; i += 256) {
            int r = i / KP, k = i % KP;
            xs[r][k] = (k < KREAL) ? Xin[(size_t)(m0 + r) * KREAL + k] : 0.f;
        }
    }
    for (int i = tid; i < KP * 64; i += 256) {
        int k = i >> 6, c = i & 63;
        wt[k][c] = (k < KREAL && c0 + c < GG) ? W[k * GG + c0 + c] : 0.f;
    }
    __syncthreads();
    const int bg = tid >> 4;                  // 16 row-groups of 4
    const int cq = tid & 15;                  // 16 col-groups of 4
    float acc[4][4];
    #pragma unroll
    for (int r = 0; r < 4; ++r)
        #pragma unroll
        for (int c = 0; c < 4; ++c) acc[r][c] = 0.f;
    for (int k4 = 0; k4 < KP; k4 += 4) {
        float xr[4][4], wc[4][4];
        #pragma unroll
        for (int r = 0; r < 4; ++r) {
            float4 v = *(const float4*)&xs[bg * 4 + r][k4];
            xr[r][0] = v.x; xr[r][1] = v.y; xr[r][2] = v.z; xr[r][3] = v.w;
        }
        #pragma unroll
        for (int j = 0; j < 4; ++j) {
            float4 v = *(const float4*)&wt[k4 + j][cq * 4];
            wc[j][0] = v.x; wc[j][1] = v.y; wc[j][2] = v.z; wc[j][3] = v.w;
        }
        #pragma unroll
        for (int r = 0; r < 4; ++r)
            #pragma unroll
            for (int j = 0; j < 4; ++j)
                #pragma unroll
                for (int c = 0; c < 4; ++c)
                    acc[r][c] += xr[r][j] * wc[j][c];
    }
    const int cb = c0 + cq * 4;
    if (cb + 3 < GG) {
        float4 bv = make_float4(bias[cb], bias[cb+1], bias[cb+2], bias[cb+3]);
        #pragma unroll
        for (int r = 0; r < 4; ++r) {
            float4 o = make_float4(acc[r][0] + bv.x, acc[r][1] + bv.y,
                                   acc[r][2] + bv.z, acc[r][3] + bv.w);
            *(float4*)&xg[(size_t)(m0 + bg * 4 + r) * XGS + cb] = o;
        }
    } else {
        #pragma unroll
        for (int r = 0; r < 4; ++r)
            #pragma unroll
            for (int j = 0; j < 4; ++j)
                if (cb + j < GG)
                    xg[(size_t)(m0 + bg * 4 + r) * XGS + cb + j] = acc[r][j] + bias[cb + j];
    }
}

// ---------------- GRU recurrence, barrier-free wave-autonomous ----------------
// WPB waves/block, RPW rows/wave. Each wave owns RPW rows end-to-end; no
// __syncthreads in the step loop (per-wave DS ops are in-order). rec item =
// RPW rows x 4 cols: per k, 1 b128 of U + RPW/4 b128 of transposed h feed
// 4*RPW FMAs. br bias in registers; h_prev in gate-lane registers.
// Output permuted to time-major: n=j*64+b -> tau=j*dn+s.
template<int WPB, int RPW>
__global__ __launch_bounds__(WPB * 64) void gru_wave(
    const float* __restrict__ xg,             // [dn*Nbatch, XGS] f32 (includes bi)
    const float* __restrict__ U,              // [50,150] f32
    const float* __restrict__ bias,           // [2,150] f32 (br = bias+150)
    float* __restrict__ Xout,                 // [MTOT,50] f32 time-major
    int dn, int Nbatch)
{
    constexpr int R   = WPB * RPW;            // rows per block
    constexpr int LPR = 64 / RPW;             // gate lanes per row
    constexpr int NU  = (HH + LPR - 1) / LPR; // gate k values per lane
    __shared__ __align__(16) float Us[HH * XGS];      // 30.4 KB
    __shared__ __align__(16) float brs[XGS];
    __shared__ __align__(16) float hsT[HH][R];        // transposed h
    __shared__ __align__(16) float rc[R][XGS];        // rec result

    const int tid  = threadIdx.x;
    const int wav  = tid >> 6;
    const int lane = tid & 63;

    for (int i = tid; i < HH * XGS; i += WPB * 64) {
        int c = i % XGS;
        Us[i] = (c < GG) ? U[(i / XGS) * GG + c] : 0.f;
    }
    for (int i = tid; i < XGS; i += WPB * 64) brs[i] = (i < GG) ? bias[GG + i] : 0.f;
    for (int i = tid; i < HH * R; i += WPB * 64) ((float*)hsT)[i] = 0.f;
    __syncthreads();                          // the only block-wide barrier

    // rec role: lanes 0..37 own a 4-col group x this wave's RPW rows
    const int cg = lane;
    float4 brv = make_float4(0.f, 0.f, 0.f, 0.f);
    if (cg < 38) brv = *(const float4*)&brs[cg * 4];

    // gate role: lane = gr*LPR + gk handles (row gr, k = gk + LPR*u)
    const int gr = lane / LPR;
    const int gk = lane % LPR;
    const int nrow = blockIdx.x * R + wav * RPW + gr;
    const int jj = nrow >> 6, bb = nrow & 63;
    float hprev[NU];
    #pragma unroll
    for (int u = 0; u < NU; ++u) hprev[u] = 0.f;

    for (int s = 0; s < dn; ++s) {
        // ---- prefetch this step's gate inputs (lands during rec) ----
        float pz[NU], pr[NU], ph[NU];
        {
            const float* g = xg + ((size_t)s * Nbatch + nrow) * XGS;
            #pragma unroll
            for (int u = 0; u < NU; ++u) {
                int k = gk + LPR * u;
                if (k < HH) { pz[u] = g[k]; pr[u] = g[HH + k]; ph[u] = g[2 * HH + k]; }
            }
        }
        // ---- rec = h @ U + br (this wave's RPW rows x 152 cols) ----
        if (cg < 38) {
            float acc[RPW][4];
            #pragma unroll
            for (int j = 0; j < RPW; ++j) {
                acc[j][0] = brv.x; acc[j][1] = brv.y; acc[j][2] = brv.z; acc[j][3] = brv.w;
            }
            #pragma unroll
            for (int k = 0; k < HH; ++k) {
                float4 w = *(const float4*)&Us[k * XGS + cg * 4];
                float wc[4] = {w.x, w.y, w.z, w.w};
                float hj[RPW];
                {
                    float4 h0 = *(const float4*)&hsT[k][wav * RPW];
                    hj[0] = h0.x; hj[1] = h0.y; hj[2] = h0.z; hj[3] = h0.w;
                    if (RPW == 8) {
                        float4 h1 = *(const float4*)&hsT[k][wav * RPW + 4];
                        hj[4] = h1.x; hj[5] = h1.y; hj[6] = h1.z; hj[7] = h1.w;
                    }
                }
                #pragma unroll
                for (int j = 0; j < RPW; ++j)
                    #pragma unroll
                    for (int cidx = 0; cidx < 4; ++cidx) acc[j][cidx] += hj[j] * wc[cidx];
            }
            #pragma unroll
            for (int j = 0; j < RPW; ++j)
                *(float4*)&rc[wav * RPW + j][cg * 4] = *(const float4*)&acc[j][0];
        }
        // ---- gates + state update + permuted global store ----
        const float* rcrow = rc[wav * RPW + gr];
        #pragma unroll
        for (int u = 0; u < NU; ++u) {
            int k = gk + LPR * u;
            if (k < HH) {
                float rcz = rcrow[k];
                float rcr = rcrow[HH + k];
                float rch = rcrow[2 * HH + k];
                float z  = sigm(pz[u] + rcz);
                float rr = sigm(pr[u] + rcr);
                float hh = tanh_f(ph[u] + rr * rch);
                float hn = z * hprev[u] + (1.f - z) * hh;
                hprev[u] = hn;
                hsT[k][wav * RPW + gr] = hn;
                Xout[((size_t)(jj * dn + s) * NB + bb) * HH + k] = hn;
            }
        }
    }
}

// ---------------- dense2 stage 1: partial sums over K-chunks ----------------
__global__ __launch_bounds__(256) void dense2_part(
    const float* __restrict__ X,              // [MTOT,50] f32 final layer (time-major)
    const float* __restrict__ W2,             // [1600,1600] f32
    float* __restrict__ hpart)                // [16,64,1600] f32 partials
{
    __shared__ __align__(16) float fsT[100][64];      // 25.6 KB  feats[f_local][b]
    __shared__ __align__(16) float wt[100][64];       // 25.6 KB  W2[f_local][c_local]
    const int c0 = blockIdx.x * 64;
    const int f0 = blockIdx.y * 100;
    const int tid = threadIdx.x;
    for (int i = tid; i < 100 * 64; i += 256) {
        int fl = i >> 6, b = i & 63;
        int f = f0 + fl;
        int j = f / HH, k = f % HH;           // feats[b, f] = X[2016+j, b, k]
        fsT[fl][b] = X[((size_t)(TTT - 32 + j) * NB + b) * HH + k];
        wt[fl][i & 63] = W2[(size_t)f * 1600 + c0 + (i & 63)];
    }
    __syncthreads();
    const int bg = tid >> 4;                  // 16 groups of 4 batch rows
    const int cq = tid & 15;                  // 16 groups of 4 cols
    float acc[4][4];
    #pragma unroll
    for (int j = 0; j < 4; ++j)
        #pragma unroll
        for (int cidx = 0; cidx < 4; ++cidx) acc[j][cidx] = 0.f;
    for (int fl = 0; fl < 100; ++fl) {
        float4 hb = *(const float4*)&fsT[fl][bg * 4];
        float4 wv = *(const float4*)&wt[fl][cq * 4];
        float hj[4] = {hb.x, hb.y, hb.z, hb.w};
        float wc[4] = {wv.x, wv.y, wv.z, wv.w};
        #pragma unroll
        for (int j = 0; j < 4; ++j)
            #pragma unroll
            for (int cidx = 0; cidx < 4; ++cidx) acc[j][cidx] += hj[j] * wc[cidx];
    }
    #pragma unroll
    for (int j = 0; j < 4; ++j) {
        size_t idx = ((size_t)blockIdx.y * 64 + bg * 4 + j) * 1600 + c0 + cq * 4;
        *(float4*)&hpart[idx] = *(const float4*)&acc[j][0];
    }
}

// ---------------- dense2 stage 2: reduce partials + bias + relu ----------------
__global__ __launch_bounds__(256) void dense2_reduce(
    const float* __restrict__ hpart,          // [16,64,1600]
    const float* __restrict__ b2,             // [1600]
    float* __restrict__ hout)                 // [64,1600]
{
    int i = blockIdx.x * 256 + threadIdx.x;   // 64*1600 total
    int b = i / 1600, c = i % 1600;
    float s = b2[c];
    #pragma unroll
    for (int p = 0; p < 16; ++p) s += hpart[((size_t)p * 64 + b) * 1600 + c];
    hout[(size_t)b * 1600 + c] = s > 0.f ? s : 0.f;
}

// ---------------- Classifier + softmax -> f32 out ----------------
__global__ __launch_bounds__(256) void cls_kernel(
    const float* __restrict__ hin,            // [64,1600] f32
    const float* __restrict__ Wc,             // [1600,41] f32
    const float* __restrict__ bc,             // [41] f32
    float* __restrict__ out)                  // [64,41] f32
{
    __shared__ float hrow[1600];
    __shared__ float part[41][8];
    __shared__ float lg[41];
    __shared__ float red[2];
    const int b = blockIdx.x;
    const int t = threadIdx.x;
    for (int i = t; i < 1600; i += 256) hrow[i] = hin[(size_t)b * 1600 + i];
    __syncthreads();
    const int cl = t % 41, ch = t / 41;       // 6 chunks x 41 classes (246 active)
    if (t < 246) {
        int fbeg = ch * 267;
        int fend = fbeg + 267; if (fend > 1600) fend = 1600;
        float a = 0.f;
        for (int f = fbeg; f < fend; ++f) a += hrow[f] * Wc[f * 41 + cl];
        part[cl][ch] = a;
    }
    __syncthreads();
    if (t < 41) {
        float s = bc[t];
        #pragma unroll
        for (int chh = 0; chh < 6; ++chh) s += part[t][chh];
        lg[t] = s;
    }
    __syncthreads();
    if (t == 0) {
        float mx = lg[0];
        for (int i = 1; i < 41; ++i) mx = fmaxf(mx, lg[i]);
        red[0] = mx;
    }
    __syncthreads();
    if (t < 41) lg[t] = expf(lg[t] - red[0]);
    __syncthreads();
    if (t == 0) {
        float sm = 0.f;
        for (int i = 0; i < 41; ++i) sm += lg[i];
        red[1] = 1.f / sm;
    }
    __syncthreads();
    if (t < 41) out[b * 41 + t] = lg[t] * red[1];
}

extern "C" void kernel_launch(void* const* d_in, const int* in_sizes, int n_in,
                              void* d_out, int out_size, void* d_ws, size_t ws_size,
                              hipStream_t stream)
{
    const float* x   = (const float*)d_in[0];    // [64,2048,128]
    const float* W0  = (const float*)d_in[1];    // [128,150]
    const float* U0  = (const float*)d_in[2];    // [50,150]
    const float* b0  = (const float*)d_in[3];    // [2,150]
    const float* Ws  = (const float*)d_in[4];    // [5,50,150]
    const float* Us  = (const float*)d_in[5];    // [5,50,150]
    const float* bs  = (const float*)d_in[6];    // [5,2,150]
    const float* W2  = (const float*)d_in[7];    // [1600,1600]
    const float* b2  = (const float*)d_in[8];    // [1600]
    const float* Wc  = (const float*)d_in[9];    // [1600,41]
    const float* bc  = (const float*)d_in[10];   // [41]

    float* xg    = (float*)d_ws;                      // MTOT*XGS f32  (79.7 MB)
    float* Xbuf  = xg + (size_t)MTOT * XGS;           // MTOT*50 f32   (26.2 MB)
    float* hbuf  = Xbuf + (size_t)MTOT * HH;          // 64*1600 f32
    float* hpart = xg;                                // 16*64*1600 f32 — xg dead by then

    static const int rates[6] = {32, 64, 128, 256, 512, 1024};

    // layer 0
    proj_gemm<D0, 128, 132, true><<<dim3(MTOT / 64, 3), 256, 0, stream>>>(x, W0, b0, xg);
    gru_wave<1, 4><<<rates[0] * NB / 4, 64, 0, stream>>>(
        xg, U0, b0, Xbuf, TTT / rates[0], rates[0] * NB);

    for (int l = 1; l < 6; ++l) {
        const float* Wl = Ws + (size_t)(l - 1) * HH * GG;
        const float* Ul = Us + (size_t)(l - 1) * HH * GG;
        const float* bl = bs + (size_t)(l - 1) * 2 * GG;
        proj_gemm<HH, 52, 52, false><<<dim3(MTOT / 64, 3), 256, 0, stream>>>(Xbuf, Wl, bl, xg);
        int rate = rates[l];
        int Nbatch = rate * NB;
        int dn = TTT / rate;
        if (l == 1) {
            gru_wave<2, 4><<<Nbatch / 8, 128, 0, stream>>>(xg, Ul, bl, Xbuf, dn, Nbatch);
        } else {
            gru_wave<4, 8><<<Nbatch / 32, 256, 0, stream>>>(xg, Ul, bl, Xbuf, dn, Nbatch);
        }
    }
    // head
    dense2_part<<<dim3(25, 16), 256, 0, stream>>>(Xbuf, W2, hpart);
    dense2_reduce<<<(64 * 1600) / 256, 256, 0, stream>>>(hpart, b2, hbuf);
    cls_kernel<<<NB, 256, 0, stream>>>(hbuf, Wc, bc, (float*)d_out);
}